// Round 1
// 407.895 us; speedup vs baseline: 1.1263x; 1.1263x over previous
//
#include <hip/hip_runtime.h>
#include <hip/hip_bf16.h>

typedef __hip_bfloat16 bf16;
typedef __attribute__((ext_vector_type(8))) short s8v;   // 8 bf16 = 4 VGPRs
typedef __attribute__((ext_vector_type(4))) float f4v;

#define NPIX 4096
#define CDIM 256
#define MN_ELEMS (1 << 20)        // CDIM * NPIX
#define QKVSTR (320L * NPIX)      // qkv per-slot stride (elems)
#define QKTSTR (64L * NPIX)       // qkt per-slot stride (elems)

// ---- async global->LDS, 16B per lane (dest = wave-uniform base + lane*16) ---
typedef __attribute__((address_space(1))) const unsigned int g_u32;
typedef __attribute__((address_space(3))) unsigned int l_u32;
__device__ __forceinline__ void glds16(const void* g, void* l) {
  __builtin_amdgcn_global_load_lds((g_u32*)g, (l_u32*)l, 16, 0, 0);
}

// ---- 8-element loaders -> bf16x8 (s8v) --------------------------------------
__device__ inline s8v ld8(const bf16* p) { return *(const s8v*)p; }
__device__ inline s8v ld8(const float* p) {
  float4 f0 = *(const float4*)p;
  float4 f1 = *(const float4*)(p + 4);
  s8v r; bf16* e = (bf16*)&r;
  e[0] = __float2bfloat16(f0.x); e[1] = __float2bfloat16(f0.y);
  e[2] = __float2bfloat16(f0.z); e[3] = __float2bfloat16(f0.w);
  e[4] = __float2bfloat16(f1.x); e[5] = __float2bfloat16(f1.y);
  e[6] = __float2bfloat16(f1.z); e[7] = __float2bfloat16(f1.w);
  return r;
}

// ---------------------------------------------------------------------------
// Fused flash-style attention: out[c][n] = sum_m V[c][m] exp(S[n][m]) / lsum[n]
// qkt: [slot][4096][64] bf16 (q at d0..31, k at d32..63).
// Vg:  rows [c][m] m-contig at slot stride QKVSTR (caller passes qkv+64*NPIX).
// out: [slot][256][4096] bf16.
// NT = n-tile (query cols per block); c-tile fixed 128; m streamed 128/step.
// grid (4096/NT, 2, nslots), 256 threads = 4 waves (wr: c/n-half, wc: m/n-half)
// LDS: k_s 8K + v_s 32K + p_s NT/64*16K = 56 KB -> 2 blocks/CU.
// Numerics identical to prior split kernels: exp without max-sub (logits are
// small), P in bf16, PV accumulated fully in f32 (better than old bf16
// split-K partials), per-row denominator in f32.
// ---------------------------------------------------------------------------
template<int NT>
__global__ __launch_bounds__(256) void fattn_k(
    const bf16* __restrict__ qkt, const bf16* __restrict__ Vg,
    bf16* __restrict__ out)
{
  constexpr int SN = NT / 32;          // per-wave sub-tiles along n
  __shared__ bf16 k_s[128 * 32];       // [m 128][32] (d=32..63 of qkt)
  __shared__ bf16 v_s[4 * 128 * 32];   // [kk][c 128][32]
  __shared__ bf16 p_s[4 * NT * 32];    // [kk][n NT][32]; Q staged here first
  float* sums = (float*)k_s;           // [2 wc][NT] after final S phase

  const int tid = threadIdx.x;
  const int z = blockIdx.z;
  const int w = tid >> 6, lane = tid & 63;
  const int l15 = lane & 15, oct = lane >> 4;
  const int wr = w >> 1, wc = w & 1;
  const int n0 = blockIdx.x * NT, c0 = blockIdx.y * 128;
  const bf16* qk = qkt + (long)z * QKTSTR;
  const bf16* Vz = Vg + (long)z * QKVSTR;
  const int srow = lane >> 2, scol = (lane & 3) * 8;

  // ---- prologue: stage Q (into p_s), K(0), V(0) ----
  #pragma unroll
  for (int g = 0; g < NT / 64; ++g)
    glds16(qk + (long)(n0 + g * 64 + (w << 4) + srow) * 64 + scol,
           p_s + g * 2048 + w * 512);
  glds16(qk + (long)((w << 4) + srow) * 64 + 32 + scol, k_s + w * 512);
  glds16(qk + (long)(64 + (w << 4) + srow) * 64 + 32 + scol, k_s + 2048 + w * 512);
  #pragma unroll
  for (int g = 0; g < 8; ++g) {
    const int kk = g & 3, rg = g >> 2;
    glds16(Vz + (long)(c0 + rg * 64 + (w << 4) + srow) * 4096 + kk * 32 + scol,
           v_s + kk * 4096 + rg * 2048 + w * 512);
  }
  __syncthreads();

  s8v qf[SN];
  #pragma unroll
  for (int st = 0; st < SN; ++st)
    qf[st] = *(const s8v*)(p_s + (wr * (NT / 2) + st * 16 + l15) * 32 + oct * 8);
  __syncthreads();   // all qf reads done before p_s is overwritten by S(0)

  f4v acc[4][SN];
  #pragma unroll
  for (int i = 0; i < 4; ++i)
    #pragma unroll
    for (int j = 0; j < SN; ++j) acc[i][j] = (f4v){0.f, 0.f, 0.f, 0.f};
  float rs[SN][4];
  #pragma unroll
  for (int st = 0; st < SN; ++st)
    #pragma unroll
    for (int r = 0; r < 4; ++r) rs[st][r] = 0.f;

  for (int i = 0; i < 32; ++i) {
    // ---- S phase: S[n][m] = q.k, exp, rowsum, write P to LDS ----
    s8v kf[4];
    #pragma unroll
    for (int nt = 0; nt < 4; ++nt)
      kf[nt] = *(const s8v*)(k_s + (wc * 64 + nt * 16 + l15) * 32 + oct * 8);
    #pragma unroll
    for (int st = 0; st < SN; ++st) {
      f4v sa[4];
      #pragma unroll
      for (int nt = 0; nt < 4; ++nt) {
        f4v zz = (f4v){0.f, 0.f, 0.f, 0.f};
        sa[nt] = __builtin_amdgcn_mfma_f32_16x16x32_bf16(qf[st], kf[nt], zz, 0, 0, 0);
      }
      const int nrow = wr * (NT / 2) + st * 16 + oct * 4;
      #pragma unroll
      for (int nt = 0; nt < 4; ++nt) {
        const int kk = wc * 2 + (nt >> 1);           // m = wc*64+nt*16+l15
        const int mc = ((nt & 1) << 4) + l15;        // m & 31
        bf16* pw = p_s + kk * (NT * 32) + nrow * 32 + mc;
        #pragma unroll
        for (int r = 0; r < 4; ++r) {
          float e = __expf(sa[nt][r]);
          rs[st][r] += e;
          pw[r * 32] = __float2bfloat16(e);
        }
      }
    }
    __syncthreads();   // (1) P ready; k_s reads done
    // ---- PV phase: acc[c][n] += V[c][m] * P[n][m], K=128 ----
    #pragma unroll
    for (int kk = 0; kk < 4; ++kk) {
      s8v vf[4], pf[SN];
      #pragma unroll
      for (int st = 0; st < 4; ++st)
        vf[st] = *(const s8v*)(v_s + kk * 4096 + (wr * 64 + st * 16 + l15) * 32 + oct * 8);
      #pragma unroll
      for (int nt = 0; nt < SN; ++nt)
        pf[nt] = *(const s8v*)(p_s + kk * (NT * 32) + (wc * (NT / 2) + nt * 16 + l15) * 32 + oct * 8);
      #pragma unroll
      for (int st = 0; st < 4; ++st)
        #pragma unroll
        for (int nt = 0; nt < SN; ++nt)
          acc[st][nt] = __builtin_amdgcn_mfma_f32_16x16x32_bf16(vf[st], pf[nt], acc[st][nt], 0, 0, 0);
    }
    __syncthreads();   // (2) v_s/p_s reads done by all waves -> safe to restage
    if (i < 31) {
      const int m1 = (i + 1) * 128;
      glds16(qk + (long)(m1 + (w << 4) + srow) * 64 + 32 + scol, k_s + w * 512);
      glds16(qk + (long)(m1 + 64 + (w << 4) + srow) * 64 + 32 + scol, k_s + 2048 + w * 512);
      #pragma unroll
      for (int g = 0; g < 8; ++g) {
        const int kk = g & 3, rg = g >> 2;
        glds16(Vz + (long)(c0 + rg * 64 + (w << 4) + srow) * 4096 + m1 + kk * 32 + scol,
               v_s + kk * 4096 + rg * 2048 + w * 512);
      }
      __syncthreads(); // (3) staged data landed (vmcnt drained by barrier)
    }
  }

  // ---- row-sum reduce across l15, combine wc halves via LDS ----
  #pragma unroll
  for (int st = 0; st < SN; ++st)
    #pragma unroll
    for (int r = 0; r < 4; ++r) {
      #pragma unroll
      for (int s = 1; s < 16; s <<= 1) rs[st][r] += __shfl_xor(rs[st][r], s);
    }
  if (l15 == 0) {
    #pragma unroll
    for (int st = 0; st < SN; ++st)
      #pragma unroll
      for (int r = 0; r < 4; ++r)
        sums[wc * NT + wr * (NT / 2) + st * 16 + oct * 4 + r] = rs[st][r];
  }
  __syncthreads();

  float rinv[SN];
  #pragma unroll
  for (int nt = 0; nt < SN; ++nt) {
    const int n = wc * (NT / 2) + nt * 16 + l15;
    rinv[nt] = 1.f / (sums[n] + sums[NT + n]);
  }
  bf16* op = out + (long)z * ((long)CDIM * NPIX);
  #pragma unroll
  for (int st = 0; st < 4; ++st) {
    const int gc = c0 + wr * 64 + st * 16 + oct * 4;
    #pragma unroll
    for (int nt = 0; nt < SN; ++nt) {
      const int gn = n0 + wc * (NT / 2) + nt * 16 + l15;
      #pragma unroll
      for (int r = 0; r < 4; ++r)
        op[(long)(gc + r) * NPIX + gn] = __float2bfloat16(acc[st][nt][r] * rinv[nt]);
    }
  }
}

// ---------------------------------------------------------------------------
// m97-class GEMM, BK=64 per barrier, batched split-K: z = slot*nsplit + slice.
// A: [M][K] k-contig (+slot*abat).  B: [N][K] k-contig (+slot*bbat).
// Cp: bf16 partials at z*M*N.  Tile 128x128, 4 waves (2x2).  (conv path only)
// ---------------------------------------------------------------------------
__global__ __launch_bounds__(256) void gemm128(
    const bf16* __restrict__ A, const bf16* __restrict__ Bm,
    bf16* __restrict__ Cp, int N, int K, int nchunk, int nsplit,
    long abat, long bbat)
{
  __shared__ bf16 a_s0[128 * 32], a_s1[128 * 32];
  __shared__ bf16 b_s0[128 * 32], b_s1[128 * 32];
  const int tid = threadIdx.x;
  const int z = blockIdx.z;
  const int bb = z / nsplit, ks = z - bb * nsplit;
  A  += bb * abat;
  Bm += bb * bbat;
  const int w = tid >> 6, lane = tid & 63;
  const int l15 = lane & 15, oct = lane >> 4;
  const int wr = w >> 1, wc = w & 1;
  const int m0 = blockIdx.y * 128, n0 = blockIdx.x * 128;
  const int kc0 = ks * nchunk, kc1 = kc0 + nchunk;

  const int srow = lane >> 2, skoff = (lane & 3) * 8;
  const long aRow0 = (long)(m0 + (w << 4) + srow) * K;
  const long aRow1 = (long)(m0 + ((w + 4) << 4) + srow) * K;
  const long bRow0 = (long)(n0 + (w << 4) + srow) * K;
  const long bRow1 = (long)(n0 + ((w + 4) << 4) + srow) * K;
  const int ldsOff0 = (w) * 512, ldsOff1 = (w + 4) * 512;

  f4v acc[4][4];
  #pragma unroll
  for (int i = 0; i < 4; ++i)
    #pragma unroll
    for (int j = 0; j < 4; ++j) acc[i][j] = (f4v){0.f, 0.f, 0.f, 0.f};

  for (int kc = kc0; kc < kc1; ++kc) {
    const int kb0 = kc * 64 + skoff;
    const int kb1 = kb0 + 32;
    glds16(A + aRow0 + kb0, a_s0 + ldsOff0);
    glds16(A + aRow1 + kb0, a_s0 + ldsOff1);
    glds16(A + aRow0 + kb1, a_s1 + ldsOff0);
    glds16(A + aRow1 + kb1, a_s1 + ldsOff1);
    glds16(Bm + bRow0 + kb0, b_s0 + ldsOff0);
    glds16(Bm + bRow1 + kb0, b_s0 + ldsOff1);
    glds16(Bm + bRow0 + kb1, b_s1 + ldsOff0);
    glds16(Bm + bRow1 + kb1, b_s1 + ldsOff1);
    __syncthreads();
    #pragma unroll
    for (int h = 0; h < 2; ++h) {
      const bf16* as = h ? a_s1 : a_s0;
      const bf16* bs = h ? b_s1 : b_s0;
      s8v af[4], bfv[4];
      #pragma unroll
      for (int st = 0; st < 4; ++st)
        af[st] = *(const s8v*)(as + (wr * 64 + st * 16 + l15) * 32 + oct * 8);
      #pragma unroll
      for (int nt = 0; nt < 4; ++nt)
        bfv[nt] = *(const s8v*)(bs + (wc * 64 + nt * 16 + l15) * 32 + oct * 8);
      #pragma unroll
      for (int st = 0; st < 4; ++st)
        #pragma unroll
        for (int nt = 0; nt < 4; ++nt)
          acc[st][nt] = __builtin_amdgcn_mfma_f32_16x16x32_bf16(af[st], bfv[nt], acc[st][nt], 0, 0, 0);
    }
    __syncthreads();
  }

  bf16* Cz = Cp + (long)z * ((long)gridDim.y * 128) * N;
  #pragma unroll
  for (int st = 0; st < 4; ++st) {
    const int gm = m0 + wr * 64 + st * 16 + oct * 4;
    #pragma unroll
    for (int nt = 0; nt < 4; ++nt) {
      const int gn = n0 + wc * 64 + nt * 16 + l15;
      #pragma unroll
      for (int r = 0; r < 4; ++r)
        Cz[(long)(gm + r) * N + gn] = __float2bfloat16(acc[st][nt][r]);
    }
  }
}

// ---------------------------------------------------------------------------
// Projection GEMM. z = slot; stage = z>>1 selects (A,bias,B) vs (A2,bias2,B2);
// batch = z&1 offsets B by bbat. QKT=1: rows gm<64 -> qkt transposed.
// ---------------------------------------------------------------------------
template<int QKT, typename TBe>
__global__ __launch_bounds__(256) void proj_k(
    const float* __restrict__ A, const float* __restrict__ A2,
    const TBe* __restrict__ B1, const TBe* __restrict__ B2,
    const float* __restrict__ bias, const float* __restrict__ bias2,
    bf16* __restrict__ Cm, bf16* __restrict__ qkt,
    int M, int N, int K, long bbat, long cbat, int nchunk)
{
  __shared__ bf16 a_s[64][40];
  __shared__ bf16 b_s[64][40];
  const int tid = threadIdx.x;
  const int z = blockIdx.z, stage = z >> 1, bat = z & 1;
  const float* Au = stage ? A2 : A;
  const float* biasu = stage ? bias2 : bias;
  const TBe* Bm = (stage ? B2 : B1) + bat * bbat;
  Cm += z * cbat;
  if (QKT) qkt += z * QKTSTR;
  const int m0 = blockIdx.y * 64, n0 = blockIdx.x * 64;
  const int w = tid >> 6, lane = tid & 63;
  const int l15 = lane & 15, oct = lane >> 4;

  f4v acc[4];
  #pragma unroll
  for (int i = 0; i < 4; ++i) acc[i] = (f4v){0.f, 0.f, 0.f, 0.f};

  const int a_i0 = tid >> 2, a_i1 = (tid & 3) * 8;
  const int b_i0 = tid >> 3, b_i1 = (tid & 7) * 8;

  s8v pa, pb;
  auto ldA = [&](int kc, s8v& d) {
    if (m0 + a_i0 < M) d = ld8(Au + (long)(m0 + a_i0) * K + kc * 32 + a_i1);
    else d = (s8v){0,0,0,0,0,0,0,0};
  };
  auto ldB = [&](int kc, s8v& d) {
    d = ld8(Bm + (long)(kc * 32 + b_i0) * N + n0 + b_i1);
  };

  ldA(0, pa); ldB(0, pb);
  for (int kc = 0; kc < nchunk; ++kc) {
    *(s8v*)&a_s[a_i0][a_i1] = pa;
    {
      const bf16* e = (const bf16*)&pb;
      #pragma unroll
      for (int j = 0; j < 8; ++j) b_s[b_i1 + j][b_i0] = e[j];
    }
    __syncthreads();
    if (kc + 1 < nchunk) { ldA(kc + 1, pa); ldB(kc + 1, pb); }
    s8v af = *(const s8v*)&a_s[w * 16 + l15][oct * 8];
    #pragma unroll
    for (int nt = 0; nt < 4; ++nt) {
      s8v bfr = *(const s8v*)&b_s[nt * 16 + l15][oct * 8];
      acc[nt] = __builtin_amdgcn_mfma_f32_16x16x32_bf16(af, bfr, acc[nt], 0, 0, 0);
    }
    __syncthreads();
  }
  const int gm_base = m0 + w * 16 + oct * 4;
  #pragma unroll
  for (int nt = 0; nt < 4; ++nt) {
    const int gn = n0 + nt * 16 + l15;
    #pragma unroll
    for (int r = 0; r < 4; ++r) {
      int gm = gm_base + r;
      if (gm < M) {
        float vv = acc[nt][r] + biasu[gm];
        if (QKT && gm < 64) qkt[(long)gn * 64 + gm] = __float2bfloat16(vv);
        else Cm[(long)gm * N + gn] = __float2bfloat16(vv);
      }
    }
  }
}

// ---- split-K reducer + bias (conv), bf16 partials, 8 elems/thread ----------
__global__ __launch_bounds__(256) void reduce_bias_k(
    const bf16* __restrict__ part, const float* __restrict__ bias,
    bf16* __restrict__ out, int nsplit)
{
  const int g8 = (blockIdx.x * 256 + threadIdx.x) * 8;
  const int b = g8 >> 20, i = g8 & (MN_ELEMS - 1);
  const bf16* p0 = part + (long)b * nsplit * MN_ELEMS + i;
  float s[8];
  { s8v v = *(const s8v*)p0; const bf16* e = (const bf16*)&v;
    #pragma unroll
    for (int j = 0; j < 8; ++j) s[j] = __bfloat162float(e[j]); }
  for (int p = 1; p < nsplit; ++p) {
    s8v v = *(const s8v*)(p0 + (long)p * MN_ELEMS); const bf16* e = (const bf16*)&v;
    #pragma unroll
    for (int j = 0; j < 8; ++j) s[j] += __bfloat162float(e[j]);
  }
  float bv = bias[i >> 12];
  s8v o; bf16* eo = (bf16*)&o;
  #pragma unroll
  for (int j = 0; j < 8; ++j) eo[j] = __float2bfloat16(s[j] + bv);
  *(s8v*)(out + g8) = o;
}

// ---- concat q/k(/v) weights+biases into fp32 [M][256] + [M] -----------------
__global__ __launch_bounds__(256) void cat_k(
    const float* __restrict__ wq, const float* __restrict__ bq,
    const float* __restrict__ wk, const float* __restrict__ bk,
    const float* __restrict__ wv, const float* __restrict__ bv,
    float* __restrict__ wcat, float* __restrict__ bcat, int M)
{
  int idx = blockIdx.x * 256 + threadIdx.x;
  int total = M << 8;
  if (idx < total) {
    int r = idx >> 8, c = idx & 255;
    float v;
    if (r < 32) v = wq[r * 256 + c];
    else if (r < 64) v = wk[(r - 32) * 256 + c];
    else v = wv[(r - 64) * 256 + c];
    wcat[idx] = v;
  } else if (idx < total + M) {
    int r = idx - total;
    bcat[r] = (r < 32) ? bq[r] : (r < 64) ? bk[r - 32] : bv[r - 64];
  }
}

// ---- both convs' weights: fp32 [O][C][9] -> bf16 [O][j*256+c] ---------------
__global__ __launch_bounds__(256) void cvtw2_k(
    const float* __restrict__ w1, const float* __restrict__ w2,
    bf16* __restrict__ o1, bf16* __restrict__ o2)
{
  const float* in = blockIdx.y ? w2 : w1;
  bf16* out = blockIdx.y ? o2 : o1;
  int idx = blockIdx.x * 256 + threadIdx.x;
  int o = idx / 2304, r = idx % 2304;
  int j = r >> 8, c = r & 255;
  out[idx] = __float2bfloat16(in[(o * 256 + c) * 9 + j]);
}

// ---------------------------------------------------------------------------
// LDS-transpose im2col, K-reordered: colT[n][j*256+c], j = dy*3+dx.
// ---------------------------------------------------------------------------
__global__ __launch_bounds__(256) void im2colT2_k(const bf16* __restrict__ x,
                                                  bf16* __restrict__ colT)
{
  __shared__ bf16 lds[3 * 66 * 66];
  const int tid = threadIdx.x;
  const int h = blockIdx.x, c0 = blockIdx.y * 64;
  x    += (long)blockIdx.z * CDIM * NPIX;
  colT += (long)blockIdx.z * 2304L * NPIX;

  if (tid < 192) {
    int row = tid >> 6, c = tid & 63;
    lds[(row * 66 + 0) * 66 + c] = __float2bfloat16(0.f);
    lds[(row * 66 + 65) * 66 + c] = __float2bfloat16(0.f);
  }
  const int w2 = tid & 31, chi = tid >> 5;
  #pragma unroll
  for (int it = 0; it < 24; ++it) {
    int row = it >> 3, cg = it & 7;
    int c = cg * 8 + chi;
    int hh = h + row - 1;
    unsigned int pix = 0;
    if ((unsigned)hh < 64u)
      pix = *(const unsigned int*)(x + (long)(c0 + c) * 4096 + hh * 64 + w2 * 2);
    const bf16* pp = (const bf16*)&pix;
    lds[(row * 66 + (w2 * 2 + 1)) * 66 + c] = pp[0];
    lds[(row * 66 + (w2 * 2 + 2)) * 66 + c] = pp[1];
  }
  __syncthreads();
  const int cg8 = tid & 7, wq = tid >> 3;
  #pragma unroll
  for (int j = 0; j < 9; ++j) {
    const int dy = j / 3, dx = j % 3;
    #pragma unroll
    for (int half = 0; half < 2; ++half) {
      int w = wq + half * 32;
      s8v v = *(const s8v*)&lds[(dy * 66 + (w + dx)) * 66 + cg8 * 8];
      *(s8v*)(colT + (long)(h * 64 + w) * 2304 + j * 256 + c0 + cg8 * 8) = v;
    }
  }
}

// ---- 16-elem row load/store helpers ----------------------------------------
__device__ inline void ld16(const bf16* p, float* v) {
  s8v r0 = *(const s8v*)p, r1 = *(const s8v*)(p + 8);
  const bf16* e0 = (const bf16*)&r0; const bf16* e1 = (const bf16*)&r1;
  #pragma unroll
  for (int j = 0; j < 8; ++j) { v[j] = __bfloat162float(e0[j]); v[8 + j] = __bfloat162float(e1[j]); }
}
__device__ inline void ld16(const float* p, float* v) {
  #pragma unroll
  for (int q = 0; q < 4; ++q) {
    float4 f = *(const float4*)(p + q * 4);
    v[q * 4 + 0] = f.x; v[q * 4 + 1] = f.y; v[q * 4 + 2] = f.z; v[q * 4 + 3] = f.w;
  }
}
__device__ inline void st16(bf16* p, const float* v) {
  s8v o0, o1v; bf16* f0 = (bf16*)&o0; bf16* f1 = (bf16*)&o1v;
  #pragma unroll
  for (int j = 0; j < 8; ++j) { f0[j] = __float2bfloat16(v[j]); f1[j] = __float2bfloat16(v[8 + j]); }
  *(s8v*)p = o0; *(s8v*)(p + 8) = o1v;
}
__device__ inline void st16(float* p, const float* v) {
  #pragma unroll
  for (int q = 0; q < 4; ++q) {
    float4 f; f.x = v[q * 4 + 0]; f.y = v[q * 4 + 1]; f.z = v[q * 4 + 2]; f.w = v[q * 4 + 3];
    *(float4*)(p + q * 4) = f;
  }
}

// ---- fused InstanceNorm: out = inorm(g*a + b) per row of 4096 --------------
template<typename TAe, typename TBe, typename TOe, int G>
__global__ __launch_bounds__(256) void inorm_k(
    const TAe* __restrict__ a, const TBe* __restrict__ b,
    const float* __restrict__ g, TOe* __restrict__ out)
{
  __shared__ float red[8];
  const int tid = threadIdx.x;
  const long base = (long)blockIdx.x * NPIX + tid * 16;
  float gv = G ? *g : 1.f;
  float va[16], vbv[16], v[16];
  ld16(a + base, va);
  ld16(b + base, vbv);
  #pragma unroll
  for (int j = 0; j < 16; ++j) v[j] = gv * va[j] + vbv[j];
  float sum = 0.f, sq = 0.f;
  #pragma unroll
  for (int j = 0; j < 16; ++j) { sum += v[j]; sq += v[j] * v[j]; }
  #pragma unroll
  for (int s = 32; s; s >>= 1) { sum += __shfl_xor(sum, s); sq += __shfl_xor(sq, s); }
  if ((tid & 63) == 0) { red[tid >> 6] = sum; red[4 + (tid >> 6)] = sq; }
  __syncthreads();
  sum = red[0] + red[1] + red[2] + red[3];
  sq  = red[4] + red[5] + red[6] + red[7];
  float mean = sum * (1.f / NPIX);
  float var  = fmaxf(sq * (1.f / NPIX) - mean * mean, 0.f);
  float rstd = rsqrtf(var + 1e-5f);
  float o[16];
  #pragma unroll
  for (int j = 0; j < 16; ++j) o[j] = (v[j] - mean) * rstd;
  st16(out + base, o);
}

// ---- host-side helpers ------------------------------------------------------
static const long CN = (long)CDIM * NPIX;

// fused flash attention: one kernel per nb slots
static void attn_core(int nb, bf16* qkv, bf16* qkt, bf16* t0, hipStream_t stream)
{
  fattn_k<64><<<dim3(64, 2, nb), dim3(256), 0, stream>>>(qkt, qkv + 64 * NPIX, t0);
}

static void run_conv(const bf16* src, const bf16* wcvt, const float* cb,
                     bf16* colT, bf16* part, bf16* dst, hipStream_t stream)
{
  dim3 TB(256);
  im2colT2_k<<<dim3(64, 4, 2), TB, 0, stream>>>(src, colT);
  gemm128<<<dim3(32, 2, 8), TB, 0, stream>>>(wcvt, colT, part, NPIX, 2304, 9, 4,
                                             0L, 2304L * NPIX);
  reduce_bias_k<<<dim3(1024), TB, 0, stream>>>(part, cb, dst, 4);
}

// ---------------------------------------------------------------------------
extern "C" void kernel_launch(void* const* d_in, const int* in_sizes, int n_in,
                              void* d_out, int out_size, void* d_ws, size_t ws_size,
                              hipStream_t stream)
{
  (void)in_sizes; (void)n_in; (void)out_size; (void)ws_size;
  const float* x = (const float*)d_in[0];
  const float* y = (const float*)d_in[1];
  auto W = [&](int i) { return (const float*)d_in[i]; };

  // total workspace need ~96 MB (no more Sb / lsum / PV partials)
  char* wp = (char*)d_ws;
  auto take = [&](size_t nbytes) { char* p = wp; wp += (nbytes + 255) & ~(size_t)255; return p; };
  bf16*  qkv   = (bf16*)take((size_t)4 * QKVSTR * 2);
  bf16*  qkt   = (bf16*)take((size_t)4 * QKTSTR * 2);
  bf16*  t0    = (bf16*)take((size_t)4 * CN * 2);
  bf16*  u1    = (bf16*)take(2 * CN * 2);
  bf16*  u2    = (bf16*)take(2 * CN * 2);
  bf16*  u3    = (bf16*)take(2 * CN * 2);
  bf16*  u4    = (bf16*)take(2 * CN * 2);
  bf16*  colT  = (bf16*)take((size_t)2 * 2304L * NPIX * 2);   // 37.7 MiB
  bf16*  wcvt1 = (bf16*)take((size_t)589824 * 2);
  bf16*  wcvt2 = (bf16*)take((size_t)589824 * 2);
  float* wcat1 = (float*)take((size_t)81920 * 4);
  float* bcat1 = (float*)take(320 * 4);
  float* wcat2 = (float*)take((size_t)81920 * 4);
  float* bcat2 = (float*)take(320 * 4);
  float* wqk   = (float*)take((size_t)16384 * 4);
  float* bqk   = (float*)take(64 * 4);
  bf16*  part  = (bf16*)take((size_t)8 * MN_ELEMS * 2);       // conv split-K
  bf16*  cvout = qkv;                                         // conv out (aliased)

  dim3 TB(256);

  // ---- prep: weight concat/convert ----
  cat_k<<<dim3(322), TB, 0, stream>>>(W(2), W(3), W(4), W(5), W(6), W(7), wcat1, bcat1, 320);
  cat_k<<<dim3(322), TB, 0, stream>>>(W(9), W(10), W(11), W(12), W(13), W(14), wcat2, bcat2, 320);
  cat_k<<<dim3(65),  TB, 0, stream>>>(W(16), W(17), W(18), W(19), nullptr, nullptr, wqk, bqk, 64);
  cvtw2_k<<<dim3(2304, 2), TB, 0, stream>>>(W(23), W(25), wcvt1, wcvt2);

  // ---- stages A+B attention together: z = stage*2 + batch ----
  proj_k<1,float><<<dim3(64,5,4), TB, 0, stream>>>(
      wcat1, wcat2, x, y, bcat1, bcat2, qkv, qkt, 320, NPIX, 256, CN, QKVSTR, 8);
  attn_core(4, qkv, qkt, t0, stream);

  // ---- out_1 / out_3 inorms ----
  inorm_k<bf16,float,bf16,1><<<dim3(512), TB, 0, stream>>>(t0, x, W(8), u1);
  inorm_k<bf16,float,bf16,1><<<dim3(512), TB, 0, stream>>>(t0 + 2 * CN, y, W(15), u3);

  // ---- conv1 -> out_2 ----
  run_conv(u1, wcvt1, W(24), colT, part, cvout, stream);
  inorm_k<bf16,bf16,bf16,0><<<dim3(512), TB, 0, stream>>>(u1, cvout, nullptr, u2);

  // ---- stage C: q/k from out_2 (transposed), v from out_3 ----
  proj_k<1,bf16><<<dim3(64,1,2), TB, 0, stream>>>(
      wqk, wqk, u2, u2, bqk, bqk, qkv, qkt, 64, NPIX, 256, CN, QKVSTR, 8);
  proj_k<0,bf16><<<dim3(64,4,2), TB, 0, stream>>>(
      W(20), W(20), u3, u3, W(21), W(21), qkv + 64 * NPIX, qkt, 256, NPIX, 256, CN, QKVSTR, 8);
  attn_core(2, qkv, qkt, t0, stream);
  inorm_k<bf16,float,bf16,1><<<dim3(512), TB, 0, stream>>>(t0, y, W(22), u1);   // o1
  inorm_k<bf16,bf16,bf16,0><<<dim3(512), TB, 0, stream>>>(u1, u3, nullptr, u4); // o2
  run_conv(u4, wcvt2, W(26), colT, part, cvout, stream);
  inorm_k<bf16,bf16,float,0><<<dim3(512), TB, 0, stream>>>(u4, cvout, nullptr, (float*)d_out);
}

// Round 2
// 396.017 us; speedup vs baseline: 1.1601x; 1.0300x over previous
//
#include <hip/hip_runtime.h>
#include <hip/hip_bf16.h>

typedef __hip_bfloat16 bf16;
typedef __attribute__((ext_vector_type(8))) short s8v;   // 8 bf16 = 4 VGPRs
typedef __attribute__((ext_vector_type(4))) short s4v;   // 4 bf16 = 8 bytes
typedef __attribute__((ext_vector_type(4))) float f4v;

#define NPIX 4096
#define CDIM 256
#define MN_ELEMS (1 << 20)        // CDIM * NPIX
#define QKVSTR (320L * NPIX)      // qkv per-slot stride (elems)
#define QKTSTR (64L * NPIX)       // qkt per-slot stride (elems)

#if __has_builtin(__builtin_amdgcn_exp2f)
#define EXP2F(x) __builtin_amdgcn_exp2f(x)
#else
#define EXP2F(x) exp2f(x)
#endif

// ---- async global->LDS, 16B per lane (dest = wave-uniform base + lane*16) ---
typedef __attribute__((address_space(1))) const unsigned int g_u32;
typedef __attribute__((address_space(3))) unsigned int l_u32;
__device__ __forceinline__ void glds16(const void* g, void* l) {
  __builtin_amdgcn_global_load_lds((g_u32*)g, (l_u32*)l, 16, 0, 0);
}

// ---- 8-element loaders -> bf16x8 (s8v) --------------------------------------
__device__ inline s8v ld8(const bf16* p) { return *(const s8v*)p; }
__device__ inline s8v ld8(const float* p) {
  float4 f0 = *(const float4*)p;
  float4 f1 = *(const float4*)(p + 4);
  s8v r; bf16* e = (bf16*)&r;
  e[0] = __float2bfloat16(f0.x); e[1] = __float2bfloat16(f0.y);
  e[2] = __float2bfloat16(f0.z); e[3] = __float2bfloat16(f0.w);
  e[4] = __float2bfloat16(f1.x); e[5] = __float2bfloat16(f1.y);
  e[6] = __float2bfloat16(f1.z); e[7] = __float2bfloat16(f1.w);
  return r;
}

// ---------------------------------------------------------------------------
// Fused flash-style attention: out[c][n] = sum_m V[c][m] exp(S[n][m]) / lsum[n]
// qkt: [slot][4096][64] bf16 (q*log2e at d0..31, k at d32..63).
// Vg:  rows [c][m] m-contig at slot stride QKVSTR (caller passes qkv+64*NPIX).
// out: [slot][256][4096] bf16.
// S computed TRANSPOSED (mfma(k,q)): lane holds 4 consecutive m at fixed n ->
// P written as swizzled ds_write_b64 (conflict-free; was 32x b16 @8-way).
// Swizzle: byte ^= ((n>>1)&3)<<4, intra-64B-row, same XOR on PV b128 reads.
// grid (4096/NT, 2, nslots), 256 threads = 4 waves (wr: n-half, wc: m-half).
// LDS: k_s 8K + v_s 32K + p_s 16K = 56 KB -> 2 blocks/CU.
// ---------------------------------------------------------------------------
template<int NT>
__global__ __launch_bounds__(256) void fattn_k(
    const bf16* __restrict__ qkt, const bf16* __restrict__ Vg,
    bf16* __restrict__ out)
{
  constexpr int SN = NT / 32;          // per-wave sub-tiles along n
  __shared__ bf16 k_s[128 * 32];       // [m 128][32] (d=32..63 of qkt)
  __shared__ bf16 v_s[4 * 128 * 32];   // [kk][c 128][32]
  __shared__ bf16 p_s[4 * NT * 32];    // [kk][n NT][32 m]; Q staged here first
  float* sums = (float*)k_s;           // [2 wc][NT] after final S phase

  const int tid = threadIdx.x;
  const int z = blockIdx.z;
  const int w = tid >> 6, lane = tid & 63;
  const int l15 = lane & 15, oct = lane >> 4;
  const int wr = w >> 1, wc = w & 1;
  const int n0 = blockIdx.x * NT, c0 = blockIdx.y * 128;
  const bf16* qk = qkt + (long)z * QKTSTR;
  const bf16* Vz = Vg + (long)z * QKVSTR;
  const int srow = lane >> 2, scol = (lane & 3) * 8;

  // ---- prologue: stage Q (into p_s, linear), K(0), V(0) ----
  #pragma unroll
  for (int g = 0; g < NT / 64; ++g)
    glds16(qk + (long)(n0 + g * 64 + (w << 4) + srow) * 64 + scol,
           p_s + g * 2048 + w * 512);
  glds16(qk + (long)((w << 4) + srow) * 64 + 32 + scol, k_s + w * 512);
  glds16(qk + (long)(64 + (w << 4) + srow) * 64 + 32 + scol, k_s + 2048 + w * 512);
  #pragma unroll
  for (int g = 0; g < 8; ++g) {
    const int kk = g & 3, rg = g >> 2;
    glds16(Vz + (long)(c0 + rg * 64 + (w << 4) + srow) * 4096 + kk * 32 + scol,
           v_s + kk * 4096 + rg * 2048 + w * 512);
  }
  __syncthreads();

  s8v qf[SN];
  #pragma unroll
  for (int st = 0; st < SN; ++st)
    qf[st] = *(const s8v*)(p_s + (wr * (NT / 2) + st * 16 + l15) * 32 + oct * 8);
  __syncthreads();   // all qf reads done before p_s is overwritten by P(0)

  f4v acc[4][SN];
  #pragma unroll
  for (int i = 0; i < 4; ++i)
    #pragma unroll
    for (int j = 0; j < SN; ++j) acc[i][j] = (f4v){0.f, 0.f, 0.f, 0.f};
  float rs[SN];
  #pragma unroll
  for (int st = 0; st < SN; ++st) rs[st] = 0.f;

  for (int i = 0; i < 32; ++i) {
    // ---- S^T phase: S[m][n] = k.q (pre-scaled by log2e), exp2, pack, write --
    s8v kf[4];
    #pragma unroll
    for (int nt = 0; nt < 4; ++nt)
      kf[nt] = *(const s8v*)(k_s + (wc * 64 + nt * 16 + l15) * 32 + oct * 8);
    #pragma unroll
    for (int st = 0; st < SN; ++st) {
      const int n = wr * (NT / 2) + st * 16 + l15;     // P row (lane-fixed)
      const int sw = ((n >> 1) & 3) << 4;              // intra-row byte XOR
      f4v sa[4];
      __builtin_amdgcn_s_setprio(1);
      #pragma unroll
      for (int nt = 0; nt < 4; ++nt) {
        f4v zz = (f4v){0.f, 0.f, 0.f, 0.f};
        sa[nt] = __builtin_amdgcn_mfma_f32_16x16x32_bf16(kf[nt], qf[st], zz, 0, 0, 0);
      }
      __builtin_amdgcn_s_setprio(0);
      #pragma unroll
      for (int nt = 0; nt < 4; ++nt) {
        const int kk = wc * 2 + (nt >> 1);             // m = wc*64+nt*16+oct*4+r
        int byte = kk * (NT * 64) + n * 64 + (nt & 1) * 32 + oct * 8;
        byte ^= sw;
        s4v pk; bf16* pe = (bf16*)&pk;
        float rsum = 0.f;
        #pragma unroll
        for (int r = 0; r < 4; ++r) {
          float e = EXP2F(sa[nt][r]);
          rsum += e;
          pe[r] = __float2bfloat16(e);
        }
        rs[st] += rsum;
        *(s4v*)((char*)p_s + byte) = pk;
      }
    }
    __syncthreads();   // (1) P ready; k_s reads done
    // ---- PV phase: acc[c][n] += V[c][m] * P[n][m], K=128 ----
    #pragma unroll
    for (int kk = 0; kk < 4; ++kk) {
      s8v vf[4], pf[SN];
      #pragma unroll
      for (int st = 0; st < 4; ++st)
        vf[st] = *(const s8v*)(v_s + kk * 4096 + (wr * 64 + st * 16 + l15) * 32 + oct * 8);
      #pragma unroll
      for (int nt = 0; nt < SN; ++nt) {
        const int n = wc * (NT / 2) + nt * 16 + l15;
        int byte = kk * (NT * 64) + n * 64 + oct * 16;
        byte ^= ((n >> 1) & 3) << 4;
        pf[nt] = *(const s8v*)((const char*)p_s + byte);
      }
      __builtin_amdgcn_s_setprio(1);
      #pragma unroll
      for (int st = 0; st < 4; ++st)
        #pragma unroll
        for (int nt = 0; nt < SN; ++nt)
          acc[st][nt] = __builtin_amdgcn_mfma_f32_16x16x32_bf16(vf[st], pf[nt], acc[st][nt], 0, 0, 0);
      __builtin_amdgcn_s_setprio(0);
    }
    __syncthreads();   // (2) v_s/p_s reads done by all waves -> safe to restage
    if (i < 31) {
      const int m1 = (i + 1) * 128;
      glds16(qk + (long)(m1 + (w << 4) + srow) * 64 + 32 + scol, k_s + w * 512);
      glds16(qk + (long)(m1 + 64 + (w << 4) + srow) * 64 + 32 + scol, k_s + 2048 + w * 512);
      #pragma unroll
      for (int g = 0; g < 8; ++g) {
        const int kk = g & 3, rg = g >> 2;
        glds16(Vz + (long)(c0 + rg * 64 + (w << 4) + srow) * 4096 + m1 + kk * 32 + scol,
               v_s + kk * 4096 + rg * 2048 + w * 512);
      }
      __syncthreads(); // (3) staged data landed (vmcnt drained by barrier)
    }
  }

  // ---- row-sum: lane holds partial for n=l15-row; reduce across octs -------
  #pragma unroll
  for (int st = 0; st < SN; ++st) {
    rs[st] += __shfl_xor(rs[st], 16);
    rs[st] += __shfl_xor(rs[st], 32);
  }
  if (lane < 16) {
    #pragma unroll
    for (int st = 0; st < SN; ++st)
      sums[wc * NT + wr * (NT / 2) + st * 16 + l15] = rs[st];
  }
  __syncthreads();

  float rinv[SN];
  #pragma unroll
  for (int nt = 0; nt < SN; ++nt) {
    const int n = wc * (NT / 2) + nt * 16 + l15;
    rinv[nt] = 1.f / (sums[n] + sums[NT + n]);
  }
  bf16* op = out + (long)z * ((long)CDIM * NPIX);
  #pragma unroll
  for (int st = 0; st < 4; ++st) {
    const int gc = c0 + wr * 64 + st * 16 + oct * 4;
    #pragma unroll
    for (int nt = 0; nt < SN; ++nt) {
      const int gn = n0 + wc * (NT / 2) + nt * 16 + l15;
      #pragma unroll
      for (int r = 0; r < 4; ++r)
        op[(long)(gc + r) * NPIX + gn] = __float2bfloat16(acc[st][nt][r] * rinv[nt]);
    }
  }
}

// ---------------------------------------------------------------------------
// m97-class GEMM, BK=64 per barrier, batched split-K: z = slot*nsplit + slice.
// A: [M][K] k-contig (+slot*abat).  B: [N][K] k-contig (+slot*bbat).
// Cp: bf16 partials at z*M*N.  Tile 128x128, 4 waves (2x2).  (conv path only)
// ---------------------------------------------------------------------------
__global__ __launch_bounds__(256) void gemm128(
    const bf16* __restrict__ A, const bf16* __restrict__ Bm,
    bf16* __restrict__ Cp, int N, int K, int nchunk, int nsplit,
    long abat, long bbat)
{
  __shared__ bf16 a_s0[128 * 32], a_s1[128 * 32];
  __shared__ bf16 b_s0[128 * 32], b_s1[128 * 32];
  const int tid = threadIdx.x;
  const int z = blockIdx.z;
  const int bb = z / nsplit, ks = z - bb * nsplit;
  A  += bb * abat;
  Bm += bb * bbat;
  const int w = tid >> 6, lane = tid & 63;
  const int l15 = lane & 15, oct = lane >> 4;
  const int wr = w >> 1, wc = w & 1;
  const int m0 = blockIdx.y * 128, n0 = blockIdx.x * 128;
  const int kc0 = ks * nchunk, kc1 = kc0 + nchunk;

  const int srow = lane >> 2, skoff = (lane & 3) * 8;
  const long aRow0 = (long)(m0 + (w << 4) + srow) * K;
  const long aRow1 = (long)(m0 + ((w + 4) << 4) + srow) * K;
  const long bRow0 = (long)(n0 + (w << 4) + srow) * K;
  const long bRow1 = (long)(n0 + ((w + 4) << 4) + srow) * K;
  const int ldsOff0 = (w) * 512, ldsOff1 = (w + 4) * 512;

  f4v acc[4][4];
  #pragma unroll
  for (int i = 0; i < 4; ++i)
    #pragma unroll
    for (int j = 0; j < 4; ++j) acc[i][j] = (f4v){0.f, 0.f, 0.f, 0.f};

  for (int kc = kc0; kc < kc1; ++kc) {
    const int kb0 = kc * 64 + skoff;
    const int kb1 = kb0 + 32;
    glds16(A + aRow0 + kb0, a_s0 + ldsOff0);
    glds16(A + aRow1 + kb0, a_s0 + ldsOff1);
    glds16(A + aRow0 + kb1, a_s1 + ldsOff0);
    glds16(A + aRow1 + kb1, a_s1 + ldsOff1);
    glds16(Bm + bRow0 + kb0, b_s0 + ldsOff0);
    glds16(Bm + bRow1 + kb0, b_s0 + ldsOff1);
    glds16(Bm + bRow0 + kb1, b_s1 + ldsOff0);
    glds16(Bm + bRow1 + kb1, b_s1 + ldsOff1);
    __syncthreads();
    #pragma unroll
    for (int h = 0; h < 2; ++h) {
      const bf16* as = h ? a_s1 : a_s0;
      const bf16* bs = h ? b_s1 : b_s0;
      s8v af[4], bfv[4];
      #pragma unroll
      for (int st = 0; st < 4; ++st)
        af[st] = *(const s8v*)(as + (wr * 64 + st * 16 + l15) * 32 + oct * 8);
      #pragma unroll
      for (int nt = 0; nt < 4; ++nt)
        bfv[nt] = *(const s8v*)(bs + (wc * 64 + nt * 16 + l15) * 32 + oct * 8);
      #pragma unroll
      for (int st = 0; st < 4; ++st)
        #pragma unroll
        for (int nt = 0; nt < 4; ++nt)
          acc[st][nt] = __builtin_amdgcn_mfma_f32_16x16x32_bf16(af[st], bfv[nt], acc[st][nt], 0, 0, 0);
    }
    __syncthreads();
  }

  bf16* Cz = Cp + (long)z * ((long)gridDim.y * 128) * N;
  #pragma unroll
  for (int st = 0; st < 4; ++st) {
    const int gm = m0 + wr * 64 + st * 16 + oct * 4;
    #pragma unroll
    for (int nt = 0; nt < 4; ++nt) {
      const int gn = n0 + wc * 64 + nt * 16 + l15;
      #pragma unroll
      for (int r = 0; r < 4; ++r)
        Cz[(long)(gm + r) * N + gn] = __float2bfloat16(acc[st][nt][r]);
    }
  }
}

// ---------------------------------------------------------------------------
// Projection GEMM. z = slot; stage = z>>1 selects (A,bias,B) vs (A2,bias2,B2);
// batch = z&1 offsets B by bbat. QKT=1: rows gm<64 -> qkt transposed, with the
// q rows (gm<32) pre-scaled by log2(e) so fattn can use raw v_exp_f32.
// ---------------------------------------------------------------------------
template<int QKT, typename TBe>
__global__ __launch_bounds__(256) void proj_k(
    const float* __restrict__ A, const float* __restrict__ A2,
    const TBe* __restrict__ B1, const TBe* __restrict__ B2,
    const float* __restrict__ bias, const float* __restrict__ bias2,
    bf16* __restrict__ Cm, bf16* __restrict__ qkt,
    int M, int N, int K, long bbat, long cbat, int nchunk)
{
  __shared__ bf16 a_s[64][40];
  __shared__ bf16 b_s[64][40];
  const int tid = threadIdx.x;
  const int z = blockIdx.z, stage = z >> 1, bat = z & 1;
  const float* Au = stage ? A2 : A;
  const float* biasu = stage ? bias2 : bias;
  const TBe* Bm = (stage ? B2 : B1) + bat * bbat;
  Cm += z * cbat;
  if (QKT) qkt += z * QKTSTR;
  const int m0 = blockIdx.y * 64, n0 = blockIdx.x * 64;
  const int w = tid >> 6, lane = tid & 63;
  const int l15 = lane & 15, oct = lane >> 4;

  f4v acc[4];
  #pragma unroll
  for (int i = 0; i < 4; ++i) acc[i] = (f4v){0.f, 0.f, 0.f, 0.f};

  const int a_i0 = tid >> 2, a_i1 = (tid & 3) * 8;
  const int b_i0 = tid >> 3, b_i1 = (tid & 7) * 8;

  s8v pa, pb;
  auto ldA = [&](int kc, s8v& d) {
    if (m0 + a_i0 < M) d = ld8(Au + (long)(m0 + a_i0) * K + kc * 32 + a_i1);
    else d = (s8v){0,0,0,0,0,0,0,0};
  };
  auto ldB = [&](int kc, s8v& d) {
    d = ld8(Bm + (long)(kc * 32 + b_i0) * N + n0 + b_i1);
  };

  ldA(0, pa); ldB(0, pb);
  for (int kc = 0; kc < nchunk; ++kc) {
    *(s8v*)&a_s[a_i0][a_i1] = pa;
    {
      const bf16* e = (const bf16*)&pb;
      #pragma unroll
      for (int j = 0; j < 8; ++j) b_s[b_i1 + j][b_i0] = e[j];
    }
    __syncthreads();
    if (kc + 1 < nchunk) { ldA(kc + 1, pa); ldB(kc + 1, pb); }
    s8v af = *(const s8v*)&a_s[w * 16 + l15][oct * 8];
    #pragma unroll
    for (int nt = 0; nt < 4; ++nt) {
      s8v bfr = *(const s8v*)&b_s[nt * 16 + l15][oct * 8];
      acc[nt] = __builtin_amdgcn_mfma_f32_16x16x32_bf16(af, bfr, acc[nt], 0, 0, 0);
    }
    __syncthreads();
  }
  const int gm_base = m0 + w * 16 + oct * 4;
  #pragma unroll
  for (int nt = 0; nt < 4; ++nt) {
    const int gn = n0 + nt * 16 + l15;
    #pragma unroll
    for (int r = 0; r < 4; ++r) {
      int gm = gm_base + r;
      if (gm < M) {
        float vv = acc[nt][r] + biasu[gm];
        if (QKT && gm < 64) {
          float vv2 = (gm < 32) ? vv * 1.44269504f : vv;   // q *= log2(e)
          qkt[(long)gn * 64 + gm] = __float2bfloat16(vv2);
        } else {
          Cm[(long)gm * N + gn] = __float2bfloat16(vv);
        }
      }
    }
  }
}

// ---- split-K reducer + bias (conv), bf16 partials, 8 elems/thread ----------
__global__ __launch_bounds__(256) void reduce_bias_k(
    const bf16* __restrict__ part, const float* __restrict__ bias,
    bf16* __restrict__ out, int nsplit)
{
  const int g8 = (blockIdx.x * 256 + threadIdx.x) * 8;
  const int b = g8 >> 20, i = g8 & (MN_ELEMS - 1);
  const bf16* p0 = part + (long)b * nsplit * MN_ELEMS + i;
  float s[8];
  { s8v v = *(const s8v*)p0; const bf16* e = (const bf16*)&v;
    #pragma unroll
    for (int j = 0; j < 8; ++j) s[j] = __bfloat162float(e[j]); }
  for (int p = 1; p < nsplit; ++p) {
    s8v v = *(const s8v*)(p0 + (long)p * MN_ELEMS); const bf16* e = (const bf16*)&v;
    #pragma unroll
    for (int j = 0; j < 8; ++j) s[j] += __bfloat162float(e[j]);
  }
  float bv = bias[i >> 12];
  s8v o; bf16* eo = (bf16*)&o;
  #pragma unroll
  for (int j = 0; j < 8; ++j) eo[j] = __float2bfloat16(s[j] + bv);
  *(s8v*)(out + g8) = o;
}

// ---- concat q/k(/v) weights+biases into fp32 [M][256] + [M] -----------------
__global__ __launch_bounds__(256) void cat_k(
    const float* __restrict__ wq, const float* __restrict__ bq,
    const float* __restrict__ wk, const float* __restrict__ bk,
    const float* __restrict__ wv, const float* __restrict__ bv,
    float* __restrict__ wcat, float* __restrict__ bcat, int M)
{
  int idx = blockIdx.x * 256 + threadIdx.x;
  int total = M << 8;
  if (idx < total) {
    int r = idx >> 8, c = idx & 255;
    float v;
    if (r < 32) v = wq[r * 256 + c];
    else if (r < 64) v = wk[(r - 32) * 256 + c];
    else v = wv[(r - 64) * 256 + c];
    wcat[idx] = v;
  } else if (idx < total + M) {
    int r = idx - total;
    bcat[r] = (r < 32) ? bq[r] : (r < 64) ? bk[r - 32] : bv[r - 64];
  }
}

// ---- both convs' weights: fp32 [O][C][9] -> bf16 [O][j*256+c] ---------------
__global__ __launch_bounds__(256) void cvtw2_k(
    const float* __restrict__ w1, const float* __restrict__ w2,
    bf16* __restrict__ o1, bf16* __restrict__ o2)
{
  const float* in = blockIdx.y ? w2 : w1;
  bf16* out = blockIdx.y ? o2 : o1;
  int idx = blockIdx.x * 256 + threadIdx.x;
  int o = idx / 2304, r = idx % 2304;
  int j = r >> 8, c = r & 255;
  out[idx] = __float2bfloat16(in[(o * 256 + c) * 9 + j]);
}

// ---------------------------------------------------------------------------
// LDS-transpose im2col, K-reordered: colT[n][j*256+c], j = dy*3+dx.
// ---------------------------------------------------------------------------
__global__ __launch_bounds__(256) void im2colT2_k(const bf16* __restrict__ x,
                                                  bf16* __restrict__ colT)
{
  __shared__ bf16 lds[3 * 66 * 66];
  const int tid = threadIdx.x;
  const int h = blockIdx.x, c0 = blockIdx.y * 64;
  x    += (long)blockIdx.z * CDIM * NPIX;
  colT += (long)blockIdx.z * 2304L * NPIX;

  if (tid < 192) {
    int row = tid >> 6, c = tid & 63;
    lds[(row * 66 + 0) * 66 + c] = __float2bfloat16(0.f);
    lds[(row * 66 + 65) * 66 + c] = __float2bfloat16(0.f);
  }
  const int w2 = tid & 31, chi = tid >> 5;
  #pragma unroll
  for (int it = 0; it < 24; ++it) {
    int row = it >> 3, cg = it & 7;
    int c = cg * 8 + chi;
    int hh = h + row - 1;
    unsigned int pix = 0;
    if ((unsigned)hh < 64u)
      pix = *(const unsigned int*)(x + (long)(c0 + c) * 4096 + hh * 64 + w2 * 2);
    const bf16* pp = (const bf16*)&pix;
    lds[(row * 66 + (w2 * 2 + 1)) * 66 + c] = pp[0];
    lds[(row * 66 + (w2 * 2 + 2)) * 66 + c] = pp[1];
  }
  __syncthreads();
  const int cg8 = tid & 7, wq = tid >> 3;
  #pragma unroll
  for (int j = 0; j < 9; ++j) {
    const int dy = j / 3, dx = j % 3;
    #pragma unroll
    for (int half = 0; half < 2; ++half) {
      int w = wq + half * 32;
      s8v v = *(const s8v*)&lds[(dy * 66 + (w + dx)) * 66 + cg8 * 8];
      *(s8v*)(colT + (long)(h * 64 + w) * 2304 + j * 256 + c0 + cg8 * 8) = v;
    }
  }
}

// ---- 16-elem row load/store helpers ----------------------------------------
__device__ inline void ld16(const bf16* p, float* v) {
  s8v r0 = *(const s8v*)p, r1 = *(const s8v*)(p + 8);
  const bf16* e0 = (const bf16*)&r0; const bf16* e1 = (const bf16*)&r1;
  #pragma unroll
  for (int j = 0; j < 8; ++j) { v[j] = __bfloat162float(e0[j]); v[8 + j] = __bfloat162float(e1[j]); }
}
__device__ inline void ld16(const float* p, float* v) {
  #pragma unroll
  for (int q = 0; q < 4; ++q) {
    float4 f = *(const float4*)(p + q * 4);
    v[q * 4 + 0] = f.x; v[q * 4 + 1] = f.y; v[q * 4 + 2] = f.z; v[q * 4 + 3] = f.w;
  }
}
__device__ inline void st16(bf16* p, const float* v) {
  s8v o0, o1v; bf16* f0 = (bf16*)&o0; bf16* f1 = (bf16*)&o1v;
  #pragma unroll
  for (int j = 0; j < 8; ++j) { f0[j] = __float2bfloat16(v[j]); f1[j] = __float2bfloat16(v[8 + j]); }
  *(s8v*)p = o0; *(s8v*)(p + 8) = o1v;
}
__device__ inline void st16(float* p, const float* v) {
  #pragma unroll
  for (int q = 0; q < 4; ++q) {
    float4 f; f.x = v[q * 4 + 0]; f.y = v[q * 4 + 1]; f.z = v[q * 4 + 2]; f.w = v[q * 4 + 3];
    *(float4*)(p + q * 4) = f;
  }
}

// ---- fused InstanceNorm: out = inorm(g*a + b) per row of 4096 --------------
template<typename TAe, typename TBe, typename TOe, int G>
__global__ __launch_bounds__(256) void inorm_k(
    const TAe* __restrict__ a, const TBe* __restrict__ b,
    const float* __restrict__ g, TOe* __restrict__ out)
{
  __shared__ float red[8];
  const int tid = threadIdx.x;
  const long base = (long)blockIdx.x * NPIX + tid * 16;
  float gv = G ? *g : 1.f;
  float va[16], vbv[16], v[16];
  ld16(a + base, va);
  ld16(b + base, vbv);
  #pragma unroll
  for (int j = 0; j < 16; ++j) v[j] = gv * va[j] + vbv[j];
  float sum = 0.f, sq = 0.f;
  #pragma unroll
  for (int j = 0; j < 16; ++j) { sum += v[j]; sq += v[j] * v[j]; }
  #pragma unroll
  for (int s = 32; s; s >>= 1) { sum += __shfl_xor(sum, s); sq += __shfl_xor(sq, s); }
  if ((tid & 63) == 0) { red[tid >> 6] = sum; red[4 + (tid >> 6)] = sq; }
  __syncthreads();
  sum = red[0] + red[1] + red[2] + red[3];
  sq  = red[4] + red[5] + red[6] + red[7];
  float mean = sum * (1.f / NPIX);
  float var  = fmaxf(sq * (1.f / NPIX) - mean * mean, 0.f);
  float rstd = rsqrtf(var + 1e-5f);
  float o[16];
  #pragma unroll
  for (int j = 0; j < 16; ++j) o[j] = (v[j] - mean) * rstd;
  st16(out + base, o);
}

// ---- host-side helpers ------------------------------------------------------
static const long CN = (long)CDIM * NPIX;

// fused flash attention: one kernel per nb slots
static void attn_core(int nb, bf16* qkv, bf16* qkt, bf16* t0, hipStream_t stream)
{
  fattn_k<64><<<dim3(64, 2, nb), dim3(256), 0, stream>>>(qkt, qkv + 64 * NPIX, t0);
}

static void run_conv(const bf16* src, const bf16* wcvt, const float* cb,
                     bf16* colT, bf16* part, bf16* dst, hipStream_t stream)
{
  dim3 TB(256);
  im2colT2_k<<<dim3(64, 4, 2), TB, 0, stream>>>(src, colT);
  gemm128<<<dim3(32, 2, 8), TB, 0, stream>>>(wcvt, colT, part, NPIX, 2304, 9, 4,
                                             0L, 2304L * NPIX);
  reduce_bias_k<<<dim3(1024), TB, 0, stream>>>(part, cb, dst, 4);
}

// ---------------------------------------------------------------------------
extern "C" void kernel_launch(void* const* d_in, const int* in_sizes, int n_in,
                              void* d_out, int out_size, void* d_ws, size_t ws_size,
                              hipStream_t stream)
{
  (void)in_sizes; (void)n_in; (void)out_size; (void)ws_size;
  const float* x = (const float*)d_in[0];
  const float* y = (const float*)d_in[1];
  auto W = [&](int i) { return (const float*)d_in[i]; };

  char* wp = (char*)d_ws;
  auto take = [&](size_t nbytes) { char* p = wp; wp += (nbytes + 255) & ~(size_t)255; return p; };
  bf16*  qkv   = (bf16*)take((size_t)4 * QKVSTR * 2);
  bf16*  qkt   = (bf16*)take((size_t)4 * QKTSTR * 2);
  bf16*  t0    = (bf16*)take((size_t)4 * CN * 2);
  bf16*  u1    = (bf16*)take(2 * CN * 2);
  bf16*  u2    = (bf16*)take(2 * CN * 2);
  bf16*  u3    = (bf16*)take(2 * CN * 2);
  bf16*  u4    = (bf16*)take(2 * CN * 2);
  bf16*  colT  = (bf16*)take((size_t)2 * 2304L * NPIX * 2);   // 37.7 MiB
  bf16*  wcvt1 = (bf16*)take((size_t)589824 * 2);
  bf16*  wcvt2 = (bf16*)take((size_t)589824 * 2);
  float* wcat1 = (float*)take((size_t)81920 * 4);
  float* bcat1 = (float*)take(320 * 4);
  float* wcat2 = (float*)take((size_t)81920 * 4);
  float* bcat2 = (float*)take(320 * 4);
  float* wqk   = (float*)take((size_t)16384 * 4);
  float* bqk   = (float*)take(64 * 4);
  bf16*  part  = (bf16*)take((size_t)8 * MN_ELEMS * 2);       // conv split-K
  bf16*  cvout = qkv;                                         // conv out (aliased)

  dim3 TB(256);

  // ---- prep: weight concat/convert ----
  cat_k<<<dim3(322), TB, 0, stream>>>(W(2), W(3), W(4), W(5), W(6), W(7), wcat1, bcat1, 320);
  cat_k<<<dim3(322), TB, 0, stream>>>(W(9), W(10), W(11), W(12), W(13), W(14), wcat2, bcat2, 320);
  cat_k<<<dim3(65),  TB, 0, stream>>>(W(16), W(17), W(18), W(19), nullptr, nullptr, wqk, bqk, 64);
  cvtw2_k<<<dim3(2304, 2), TB, 0, stream>>>(W(23), W(25), wcvt1, wcvt2);

  // ---- stages A+B attention together: z = stage*2 + batch ----
  proj_k<1,float><<<dim3(64,5,4), TB, 0, stream>>>(
      wcat1, wcat2, x, y, bcat1, bcat2, qkv, qkt, 320, NPIX, 256, CN, QKVSTR, 8);
  attn_core(4, qkv, qkt, t0, stream);

  // ---- out_1 / out_3 inorms ----
  inorm_k<bf16,float,bf16,1><<<dim3(512), TB, 0, stream>>>(t0, x, W(8), u1);
  inorm_k<bf16,float,bf16,1><<<dim3(512), TB, 0, stream>>>(t0 + 2 * CN, y, W(15), u3);

  // ---- conv1 -> out_2 ----
  run_conv(u1, wcvt1, W(24), colT, part, cvout, stream);
  inorm_k<bf16,bf16,bf16,0><<<dim3(512), TB, 0, stream>>>(u1, cvout, nullptr, u2);

  // ---- stage C: q/k from out_2 (transposed), v from out_3 ----
  proj_k<1,bf16><<<dim3(64,1,2), TB, 0, stream>>>(
      wqk, wqk, u2, u2, bqk, bqk, qkv, qkt, 64, NPIX, 256, CN, QKVSTR, 8);
  proj_k<0,bf16><<<dim3(64,4,2), TB, 0, stream>>>(
      W(20), W(20), u3, u3, W(21), W(21), qkv + 64 * NPIX, qkt, 256, NPIX, 256, CN, QKVSTR, 8);
  attn_core(2, qkv, qkt, t0, stream);
  inorm_k<bf16,float,bf16,1><<<dim3(512), TB, 0, stream>>>(t0, y, W(22), u1);   // o1
  inorm_k<bf16,bf16,bf16,0><<<dim3(512), TB, 0, stream>>>(u1, u3, nullptr, u4); // o2
  run_conv(u4, wcvt2, W(26), colT, part, cvout, stream);
  inorm_k<bf16,bf16,float,0><<<dim3(512), TB, 0, stream>>>(u4, cvout, nullptr, (float*)d_out);
}